// Round 6
// baseline (186.579 us; speedup 1.0000x reference)
//
#include <hip/hip_runtime.h>
#include <stdint.h>

// IDCT (DCT-III, DREAMPlace scaling) via even/odd split, fully fused:
//   E[m][p] = sum_{n even} x[m][n]*c(n,p),  O[m][p] = sum_{n odd} ...,
//   out[p] = E+O, out[N-1-p] = E-O   (c(n,N-1-p) = (-1)^n c(n,p)).
// R11 (from R8-R10: three different schedules all ~72-76us => LDS-traffic
// floor, not scheduling. Per CU-iter: 128 ds_read_b128 (~1540cy) + 64KB
// GLDS writes (~600cy) ~= 2100-2300cy vs 2780 measured):
//   CUT THE TRAFFIC: B (cosine tables) is pre-tiled in the EXACT fragment
//   layout, so waves load B-frags straight from global into VGPRs
//   (global_load_dwordx4), no LDS bounce. The 2 m-waves of a block read
//   identical B lines in barrier-lockstep -> L1 (32KB/CU) provides the
//   sharing LDS used to. Removes half the ds_reads and half the GLDS
//   writes. A stays in LDS (2-wave sharing kept). B-regs double-buffered
//   (two NAMED frag sets, static indexing), depth-2 prefetch folded into
//   the counted-vmcnt pipeline: outstanding = stage(t+1)4 + bload(t+1)8
//   = 12 -> WAITVM(12) retires exactly tile t. Numerics bit-identical.
// New floors/CU-iter: LDS ~1000cy, MFMA 1240cy, L2 1170-1715cy.
// ws: Ae_t 16MB | Ao_t 16MB | Ce_t 8MB | Co_t 8MB = 48MB.
// Tile layout: plane[(tile = bt*64 + kb)*4096 + g*1024 + r*8 + j]
//   = elem(row=r, k=kb*32+g*8+j) of the (bt,kb) 128x32 tile.

#define Md 4096
#define Nfull 4096
#define Ph 2048   // half output width
#define Kh 2048   // half reduction
#define BM 128
#define BN 128
#define BK 32
#define NKB 64    // Kh/BK k-blocks
#define TILE 4096 // elems per tile (128 rows x 32 k)

typedef short bf16x8 __attribute__((ext_vector_type(8)));
typedef float floatx4 __attribute__((ext_vector_type(4)));
typedef unsigned short ushort_t;

__device__ __forceinline__ ushort_t f2bf(float f) {
  union { float f; uint32_t u; } v; v.f = f;
  uint32_t u = v.u;
  return (ushort_t)((u + 0x7fffu + ((u >> 16) & 1u)) >> 16);
}

// blocks [0,2048): deinterleave x into tiled Ae/Ao. Block=(bm,kb) tile pair;
//   thread t: row r=t>>1, half h=t&1 -> reads 32 consecutive floats (128B),
//   writes 2 int4 per plane at tiled offsets (two 512B segments/instr).
// blocks [2048,4096): cosine tables straight into tiled layout, 2 chunks/thr.
__global__ __launch_bounds__(256) void prep_kernel(const float* __restrict__ x,
                                                   ushort_t* __restrict__ Ae,
                                                   ushort_t* __restrict__ Ao,
                                                   ushort_t* __restrict__ Ce,
                                                   ushort_t* __restrict__ Co) {
  int b = blockIdx.x;
  int t = threadIdx.x;
  if (b < 2048) {
    int bm = b >> 6, kb = b & 63;
    int r = t >> 1, h = t & 1;
    const float4* xp = (const float4*)(x + (((size_t)(bm * 128 + r)) << 12) + kb * 64 + h * 32);
    float4 v0 = xp[0], v1 = xp[1], v2 = xp[2], v3 = xp[3];
    float4 v4 = xp[4], v5 = xp[5], v6 = xp[6], v7 = xp[7];
    union { ushort_t us[8]; int4 v; } e0, e1, o0, o1;
    e0.us[0] = f2bf(v0.x); o0.us[0] = f2bf(v0.y);
    e0.us[1] = f2bf(v0.z); o0.us[1] = f2bf(v0.w);
    e0.us[2] = f2bf(v1.x); o0.us[2] = f2bf(v1.y);
    e0.us[3] = f2bf(v1.z); o0.us[3] = f2bf(v1.w);
    e0.us[4] = f2bf(v2.x); o0.us[4] = f2bf(v2.y);
    e0.us[5] = f2bf(v2.z); o0.us[5] = f2bf(v2.w);
    e0.us[6] = f2bf(v3.x); o0.us[6] = f2bf(v3.y);
    e0.us[7] = f2bf(v3.z); o0.us[7] = f2bf(v3.w);
    e1.us[0] = f2bf(v4.x); o1.us[0] = f2bf(v4.y);
    e1.us[1] = f2bf(v4.z); o1.us[1] = f2bf(v4.w);
    e1.us[2] = f2bf(v5.x); o1.us[2] = f2bf(v5.y);
    e1.us[3] = f2bf(v5.z); o1.us[3] = f2bf(v5.w);
    e1.us[4] = f2bf(v6.x); o1.us[4] = f2bf(v6.y);
    e1.us[5] = f2bf(v6.z); o1.us[5] = f2bf(v6.w);
    e1.us[6] = f2bf(v7.x); o1.us[6] = f2bf(v7.y);
    e1.us[7] = f2bf(v7.z); o1.us[7] = f2bf(v7.w);
    size_t tb = ((size_t)(bm * 64 + kb)) << 12;      // tile base (elems)
    int c0 = (2 * h) * 1024 + r * 8;                 // g = 2h
    int c1 = c0 + 1024;                              // g = 2h+1
    *(int4*)(Ae + tb + c0) = e0.v;
    *(int4*)(Ae + tb + c1) = e1.v;
    *(int4*)(Ao + tb + c0) = o0.v;
    *(int4*)(Ao + tb + c1) = o1.v;
  } else {
    int b2 = b - 2048;
    int plane = b2 >> 10;            // 0 = Ce (even n), 1 = Co (odd n)
    int bn = (b2 & 1023) >> 6, kb = b2 & 63;
    ushort_t* T = plane ? Co : Ce;
    size_t tb = ((size_t)(bn * 64 + kb)) << 12;
    const float s = 3.14159265358979f / 8192.0f;     // pi/(2N)
#pragma unroll
    for (int half = 0; half < 2; ++half) {
      int cc = t + half * 256;       // chunk index within tile [0,512)
      int g = cc >> 7, r = cc & 127;
      int p = bn * 128 + r;
      int tp = 2 * p + 1;
      int ni = kb * 32 + g * 8;
      union { ushort_t us[8]; int4 v; } pk;
#pragma unroll
      for (int jj = 0; jj < 8; ++jj) {
        int n = 2 * (ni + jj) + plane;
        int ang = (n * tp) & 16383;  // mod 4N: exact int reduction
        float c = (n == 0) ? 1.0f : 2.0f * __cosf(s * (float)ang);
        pk.us[jj] = f2bf(c);
      }
      *(int4*)(T + tb + cc * 8) = pk.v;
    }
  }
}

// Fused dual GEMM + butterfly. Block 128m x 128p, BK=32, 4 waves 2x2,
// wave tile 64x64 per GEMM, frags 4x4, dual acc E/O.
// A double-buffered in two DISTINCT __shared__ arrays (16KB each: AsE|AsO).
// B loaded per-wave straight from pre-tiled global into VGPR frags
// (8 global_load_dwordx4/iter), double-buffered in named reg sets b0/b1.
// Counted-vmcnt depth-2: per iter outstanding = stage(t+1)[4] +
// bload(t+1)[8] = 12 -> s_waitcnt vmcnt(12), never 0 in main loop.
__global__ __launch_bounds__(256, 2) void gemm_fused(const ushort_t* __restrict__ Ae,
                                                     const ushort_t* __restrict__ Ao,
                                                     const ushort_t* __restrict__ Ce,
                                                     const ushort_t* __restrict__ Co,
                                                     float* __restrict__ out) {
  __shared__ __align__(16) ushort_t S0[8192];   // 16 KB: AsE | AsO
  __shared__ __align__(16) ushort_t S1[8192];   // 16 KB

  const int tid = threadIdx.x;
  const int wid = tid >> 6;
  const int lane = tid & 63;

  const int bm = blockIdx.y;   // m-tile index (128 rows)
  const int bn = blockIdx.x;   // p-tile index (128 cols)

  const int wm = (wid & 1) * 64;
  const int wn = (wid >> 1) * 64;
  const int lrow = lane & 15;

  floatx4 accE[4][4] = {};
  floatx4 accO[4][4] = {};

  const int lb = wid * 512;                  // wave elem base within an issue
  const ushort_t* pAe = Ae + (((size_t)bm * NKB) << 12) + (tid << 3);
  const ushort_t* pAo = Ao + (((size_t)bm * NKB) << 12) + (tid << 3);

  const int g1024 = (lane >> 4) << 10;   // k-chunk * 1024 elems
  const int rb8 = lrow << 3;

  // Per-lane B fragment base (frag f at +f*128 elems, iter t at +t*4096).
  const ushort_t* pBe = Ce + (((size_t)bn * NKB) << 12) + g1024 + rb8 + (wn << 3);
  const ushort_t* pBo = Co + (((size_t)bn * NKB) << 12) + g1024 + rb8 + (wn << 3);

#define GLDS(src, dst) __builtin_amdgcn_global_load_lds( \
      (const __attribute__((address_space(1))) void*)(src), \
      (__attribute__((address_space(3))) void*)(dst), 16, 0, 0)

#define STAGE(SB, t) do { \
    size_t so_ = ((size_t)(t)) << 12; \
    GLDS(pAe + so_, SB + lb); \
    GLDS(pAe + so_ + 2048, SB + 2048 + lb); \
    GLDS(pAo + so_, SB + 4096 + lb); \
    GLDS(pAo + so_ + 2048, SB + 4096 + 2048 + lb); \
  } while (0)

#define BLOAD(bE_, bO_, t) do { \
    const ushort_t* pe_ = pBe + (((size_t)(t)) << 12); \
    const ushort_t* po_ = pBo + (((size_t)(t)) << 12); \
    _Pragma("unroll") \
    for (int f_ = 0; f_ < 4; ++f_) { \
      bE_[f_] = *(const bf16x8*)(pe_ + f_ * 128); \
      bO_[f_] = *(const bf16x8*)(po_ + f_ * 128); \
    } } while (0)

#define COMPUTE(SB, bE_, bO_) do { \
    __builtin_amdgcn_s_setprio(1); \
    _Pragma("unroll") \
    for (int im_ = 0; im_ < 4; ++im_) { \
      int off_ = g1024 + rb8 + ((wm + im_ * 16) << 3); \
      bf16x8 aE_ = *(const bf16x8*)(SB + off_); \
      bf16x8 aO_ = *(const bf16x8*)(SB + 4096 + off_); \
      _Pragma("unroll") \
      for (int jn_ = 0; jn_ < 4; ++jn_) { \
        accE[im_][jn_] = __builtin_amdgcn_mfma_f32_16x16x32_bf16(aE_, bE_[jn_], accE[im_][jn_], 0, 0, 0); \
        accO[im_][jn_] = __builtin_amdgcn_mfma_f32_16x16x32_bf16(aO_, bO_[jn_], accO[im_][jn_], 0, 0, 0); \
      } \
    } \
    __builtin_amdgcn_s_setprio(0); \
  } while (0)

#define WAITVM(n) do { \
    asm volatile("s_waitcnt vmcnt(" #n ")" ::: "memory"); \
    __builtin_amdgcn_sched_barrier(0); \
  } while (0)

  bf16x8 bE0[4], bO0[4], bE1[4], bO1[4];

  // Prologue: stage tiles 0 and 1 (depth-2 pipeline). 24 VMEM in flight.
  STAGE(S0, 0);
  BLOAD(bE0, bO0, 0);
  STAGE(S1, 1);
  BLOAD(bE1, bO1, 1);

  for (int t = 0; t < NKB - 4; t += 2) {   // t = 0,2,...,58
    WAITVM(12);                            // tile t (stage+bload) landed
    __builtin_amdgcn_s_barrier();
    COMPUTE(S0, bE0, bO0);
    __builtin_amdgcn_s_barrier();
    STAGE(S0, t + 2);
    BLOAD(bE0, bO0, t + 2);
    WAITVM(12);                            // tile t+1 landed
    __builtin_amdgcn_s_barrier();
    COMPUTE(S1, bE1, bO1);
    __builtin_amdgcn_s_barrier();
    STAGE(S1, t + 3);
    BLOAD(bE1, bO1, t + 3);
  }
  // iters 60, 61: compute + last stages (62, 63).
  WAITVM(12);
  __builtin_amdgcn_s_barrier();
  COMPUTE(S0, bE0, bO0);
  __builtin_amdgcn_s_barrier();
  STAGE(S0, 62);
  BLOAD(bE0, bO0, 62);
  WAITVM(12);
  __builtin_amdgcn_s_barrier();
  COMPUTE(S1, bE1, bO1);
  __builtin_amdgcn_s_barrier();
  STAGE(S1, 63);
  BLOAD(bE1, bO1, 63);
  // iter 62: tile 62 landed (63 still in flight).
  WAITVM(12);
  __builtin_amdgcn_s_barrier();
  COMPUTE(S0, bE0, bO0);
  // iter 63: everything landed.
  WAITVM(0);
  __builtin_amdgcn_s_barrier();
  COMPUTE(S1, bE1, bO1);

#undef GLDS
#undef STAGE
#undef BLOAD
#undef COMPUTE
#undef WAITVM

  // Epilogue butterfly. C/D mapping: col=lane&15, row=(lane>>4)*4+r.
#pragma unroll
  for (int im = 0; im < 4; ++im) {
    int rb = bm * BM + wm + im * 16 + (lane >> 4) * 4;
#pragma unroll
    for (int jn = 0; jn < 4; ++jn) {
      int p = bn * BN + wn + jn * 16 + lrow;
      float* lo = out + (size_t)rb * Nfull + p;
      float* hi = out + (size_t)rb * Nfull + (Nfull - 1 - p);
#pragma unroll
      for (int r = 0; r < 4; ++r) {
        float e = accE[im][jn][r];
        float o = accO[im][jn][r];
        lo[(size_t)r * Nfull] = e + o;
        hi[(size_t)r * Nfull] = e - o;
      }
    }
  }
}

extern "C" void kernel_launch(void* const* d_in, const int* in_sizes, int n_in,
                              void* d_out, int out_size, void* d_ws, size_t ws_size,
                              hipStream_t stream) {
  const float* x = (const float*)d_in[0];
  float* out = (float*)d_out;
  ushort_t* Ae = (ushort_t*)d_ws;                      // 16 MB (tiled)
  ushort_t* Ao = Ae + (size_t)8 * 1024 * 1024;         // 16 MB
  ushort_t* Ce = Ao + (size_t)8 * 1024 * 1024;         // 8 MB
  ushort_t* Co = Ce + (size_t)4 * 1024 * 1024;         // 8 MB

  prep_kernel<<<4096, 256, 0, stream>>>(x, Ae, Ao, Ce, Co);

  dim3 grid(Ph / BN, Md / BM);  // 16 x 32 = 512 blocks = 2/CU
  gemm_fused<<<grid, 256, 0, stream>>>(Ae, Ao, Ce, Co, out);
}

// Round 7
// 179.911 us; speedup vs baseline: 1.0371x; 1.0371x over previous
//
#include <hip/hip_runtime.h>
#include <stdint.h>

// IDCT (DCT-III, DREAMPlace scaling) via even/odd split, fully fused:
//   E[m][p] = sum_{n even} x[m][n]*c(n,p),  O[m][p] = sum_{n odd} ...,
//   out[p] = E+O, out[N-1-p] = E-O   (c(n,N-1-p) = (-1)^n c(n,p)).
// R12 (post-mortems: R11 B-from-global REGRESSED 74->89 — L1/TCP path at
// ~64B/cy served B twice vs one LDS bounce at 256B/cy; reverted. R8-R10 all
// ~72-76us with MfmaUtil 40% and NO saturated pipe (LDS floors ~750cy of
// 2775cy/iter) => LATENCY wall at 8 waves/CU (2/SIMD, Occupancy 18%), and
// the 64x64 dual-GEMM wave tile's 128 acc VGPRs hard-cap occupancy there):
//   Same block structure (128x128, BK=32, dbuf S0/S1, counted vmcnt,
//   pre-tiled operands) but 512-THREAD blocks, 8 waves 2m x 4n (wave tile
//   64x32, dual acc = 64 VGPR). __launch_bounds__(512,4) caps VGPR at 128
//   -> 16 waves/CU (4/SIMD), 2 independent blocks/CU hiding each other's
//   stage latency. LDS read/block-iter 64->96KB (B now read by 4 n-waves)
//   but at 256B/cy that's ~750cy — cheap vs the latency being reclaimed.
//   STAGE = 4 GLDS/wave (512 thr cover one 8KB plane per issue); depth-2
//   pipeline waits vmcnt(4).
// ws: Ae_t 16MB | Ao_t 16MB | Ce_t 8MB | Co_t 8MB = 48MB.
// Tile layout: plane[(tile = bt*64 + kb)*4096 + g*1024 + r*8 + j]
//   = elem(row=r, k=kb*32+g*8+j) of the (bt,kb) 128x32 tile.

#define Md 4096
#define Nfull 4096
#define Ph 2048   // half output width
#define Kh 2048   // half reduction
#define BM 128
#define BN 128
#define BK 32
#define NKB 64    // Kh/BK k-blocks
#define TILE 4096 // elems per tile (128 rows x 32 k)

typedef short bf16x8 __attribute__((ext_vector_type(8)));
typedef float floatx4 __attribute__((ext_vector_type(4)));
typedef unsigned short ushort_t;

__device__ __forceinline__ ushort_t f2bf(float f) {
  union { float f; uint32_t u; } v; v.f = f;
  uint32_t u = v.u;
  return (ushort_t)((u + 0x7fffu + ((u >> 16) & 1u)) >> 16);
}

// blocks [0,2048): deinterleave x into tiled Ae/Ao. Block=(bm,kb) tile pair;
//   thread t: row r=t>>1, half h=t&1 -> reads 32 consecutive floats (128B),
//   writes 2 int4 per plane at tiled offsets (two 512B segments/instr).
// blocks [2048,4096): cosine tables straight into tiled layout, 2 chunks/thr.
__global__ __launch_bounds__(256) void prep_kernel(const float* __restrict__ x,
                                                   ushort_t* __restrict__ Ae,
                                                   ushort_t* __restrict__ Ao,
                                                   ushort_t* __restrict__ Ce,
                                                   ushort_t* __restrict__ Co) {
  int b = blockIdx.x;
  int t = threadIdx.x;
  if (b < 2048) {
    int bm = b >> 6, kb = b & 63;
    int r = t >> 1, h = t & 1;
    const float4* xp = (const float4*)(x + (((size_t)(bm * 128 + r)) << 12) + kb * 64 + h * 32);
    float4 v0 = xp[0], v1 = xp[1], v2 = xp[2], v3 = xp[3];
    float4 v4 = xp[4], v5 = xp[5], v6 = xp[6], v7 = xp[7];
    union { ushort_t us[8]; int4 v; } e0, e1, o0, o1;
    e0.us[0] = f2bf(v0.x); o0.us[0] = f2bf(v0.y);
    e0.us[1] = f2bf(v0.z); o0.us[1] = f2bf(v0.w);
    e0.us[2] = f2bf(v1.x); o0.us[2] = f2bf(v1.y);
    e0.us[3] = f2bf(v1.z); o0.us[3] = f2bf(v1.w);
    e0.us[4] = f2bf(v2.x); o0.us[4] = f2bf(v2.y);
    e0.us[5] = f2bf(v2.z); o0.us[5] = f2bf(v2.w);
    e0.us[6] = f2bf(v3.x); o0.us[6] = f2bf(v3.y);
    e0.us[7] = f2bf(v3.z); o0.us[7] = f2bf(v3.w);
    e1.us[0] = f2bf(v4.x); o1.us[0] = f2bf(v4.y);
    e1.us[1] = f2bf(v4.z); o1.us[1] = f2bf(v4.w);
    e1.us[2] = f2bf(v5.x); o1.us[2] = f2bf(v5.y);
    e1.us[3] = f2bf(v5.z); o1.us[3] = f2bf(v5.w);
    e1.us[4] = f2bf(v6.x); o1.us[4] = f2bf(v6.y);
    e1.us[5] = f2bf(v6.z); o1.us[5] = f2bf(v6.w);
    e1.us[6] = f2bf(v7.x); o1.us[6] = f2bf(v7.y);
    e1.us[7] = f2bf(v7.z); o1.us[7] = f2bf(v7.w);
    size_t tb = ((size_t)(bm * 64 + kb)) << 12;      // tile base (elems)
    int c0 = (2 * h) * 1024 + r * 8;                 // g = 2h
    int c1 = c0 + 1024;                              // g = 2h+1
    *(int4*)(Ae + tb + c0) = e0.v;
    *(int4*)(Ae + tb + c1) = e1.v;
    *(int4*)(Ao + tb + c0) = o0.v;
    *(int4*)(Ao + tb + c1) = o1.v;
  } else {
    int b2 = b - 2048;
    int plane = b2 >> 10;            // 0 = Ce (even n), 1 = Co (odd n)
    int bn = (b2 & 1023) >> 6, kb = b2 & 63;
    ushort_t* T = plane ? Co : Ce;
    size_t tb = ((size_t)(bn * 64 + kb)) << 12;
    const float s = 3.14159265358979f / 8192.0f;     // pi/(2N)
#pragma unroll
    for (int half = 0; half < 2; ++half) {
      int cc = t + half * 256;       // chunk index within tile [0,512)
      int g = cc >> 7, r = cc & 127;
      int p = bn * 128 + r;
      int tp = 2 * p + 1;
      int ni = kb * 32 + g * 8;
      union { ushort_t us[8]; int4 v; } pk;
#pragma unroll
      for (int jj = 0; jj < 8; ++jj) {
        int n = 2 * (ni + jj) + plane;
        int ang = (n * tp) & 16383;  // mod 4N: exact int reduction
        float c = (n == 0) ? 1.0f : 2.0f * __cosf(s * (float)ang);
        pk.us[jj] = f2bf(c);
      }
      *(int4*)(T + tb + cc * 8) = pk.v;
    }
  }
}

// Fused dual GEMM + butterfly. Block 128m x 128p, BK=32, 512 threads,
// 8 waves 2m x 4n, wave tile 64m x 32p per GEMM, frags 4x2, dual acc E/O
// (64 acc VGPRs -> 4 waves/SIMD with launch_bounds(512,4)).
// A+B double-buffered in two DISTINCT __shared__ arrays S0/S1 (32KB each:
// AsE|AsO|BsE|BsO x 4096 elems) -> NoAlias provable, no spurious vmcnt(0).
// Counted-vmcnt depth-2: STAGE = 4 GLDS/wave (each covers one full 8KB
// plane: 512 thr x 16B); main-loop wait vmcnt(4), never 0.
__global__ __launch_bounds__(512, 4) void gemm_fused(const ushort_t* __restrict__ Ae,
                                                     const ushort_t* __restrict__ Ao,
                                                     const ushort_t* __restrict__ Ce,
                                                     const ushort_t* __restrict__ Co,
                                                     float* __restrict__ out) {
  __shared__ __align__(16) ushort_t S0[16384];   // 32 KB: AsE|AsO|BsE|BsO
  __shared__ __align__(16) ushort_t S1[16384];   // 32 KB

  const int tid = threadIdx.x;
  const int wid = tid >> 6;
  const int lane = tid & 63;

  const int bm = blockIdx.y;   // m-tile index (128 rows)
  const int bn = blockIdx.x;   // p-tile index (128 cols)

  const int wm = (wid & 1) * 64;    // 2 m-wave groups
  const int wn = (wid >> 1) * 32;   // 4 n-wave groups
  const int lrow = lane & 15;

  floatx4 accE[4][2] = {};
  floatx4 accO[4][2] = {};

  const int lb = wid * 512;                  // wave elem base within a plane
  const ushort_t* pAe = Ae + (((size_t)bm * NKB) << 12) + (tid << 3);
  const ushort_t* pAo = Ao + (((size_t)bm * NKB) << 12) + (tid << 3);
  const ushort_t* pBe = Ce + (((size_t)bn * NKB) << 12) + (tid << 3);
  const ushort_t* pBo = Co + (((size_t)bn * NKB) << 12) + (tid << 3);

  const int g1024 = (lane >> 4) << 10;   // k-chunk * 1024 elems
  const int rb8 = lrow << 3;

#define GLDS(src, dst) __builtin_amdgcn_global_load_lds( \
      (const __attribute__((address_space(1))) void*)(src), \
      (__attribute__((address_space(3))) void*)(dst), 16, 0, 0)

#define STAGE(SB, t) do { \
    size_t so_ = ((size_t)(t)) << 12; \
    GLDS(pAe + so_, SB + lb); \
    GLDS(pAo + so_, SB + 4096 + lb); \
    GLDS(pBe + so_, SB + 8192 + lb); \
    GLDS(pBo + so_, SB + 12288 + lb); \
  } while (0)

#define COMPUTE(SB) do { \
    bf16x8 bE_[2], bO_[2]; \
    _Pragma("unroll") \
    for (int f_ = 0; f_ < 2; ++f_) { \
      int off_ = g1024 + rb8 + ((wn + f_ * 16) << 3); \
      bE_[f_] = *(const bf16x8*)(SB + 8192 + off_); \
      bO_[f_] = *(const bf16x8*)(SB + 12288 + off_); \
    } \
    __builtin_amdgcn_s_setprio(1); \
    _Pragma("unroll") \
    for (int im_ = 0; im_ < 4; ++im_) { \
      int off_ = g1024 + rb8 + ((wm + im_ * 16) << 3); \
      bf16x8 aE_ = *(const bf16x8*)(SB + off_); \
      bf16x8 aO_ = *(const bf16x8*)(SB + 4096 + off_); \
      _Pragma("unroll") \
      for (int jn_ = 0; jn_ < 2; ++jn_) { \
        accE[im_][jn_] = __builtin_amdgcn_mfma_f32_16x16x32_bf16(aE_, bE_[jn_], accE[im_][jn_], 0, 0, 0); \
        accO[im_][jn_] = __builtin_amdgcn_mfma_f32_16x16x32_bf16(aO_, bO_[jn_], accO[im_][jn_], 0, 0, 0); \
      } \
    } \
    __builtin_amdgcn_s_setprio(0); \
  } while (0)

#define WAITVM(n) do { \
    asm volatile("s_waitcnt vmcnt(" #n ")" ::: "memory"); \
    __builtin_amdgcn_sched_barrier(0); \
  } while (0)

  // Prologue: stage tiles 0 and 1 (depth-2 pipeline). 8 VMEM in flight.
  STAGE(S0, 0);
  STAGE(S1, 1);

  for (int t = 0; t < NKB - 4; t += 2) {   // t = 0,2,...,58
    WAITVM(4);                             // tile t landed; t+1 in flight
    __builtin_amdgcn_s_barrier();
    COMPUTE(S0);
    __builtin_amdgcn_s_barrier();
    STAGE(S0, t + 2);
    WAITVM(4);                             // tile t+1 landed; t+2 in flight
    __builtin_amdgcn_s_barrier();
    COMPUTE(S1);
    __builtin_amdgcn_s_barrier();
    STAGE(S1, t + 3);
  }
  // iters 60, 61: compute + last stages (62, 63).
  WAITVM(4);
  __builtin_amdgcn_s_barrier();
  COMPUTE(S0);
  __builtin_amdgcn_s_barrier();
  STAGE(S0, 62);
  WAITVM(4);
  __builtin_amdgcn_s_barrier();
  COMPUTE(S1);
  __builtin_amdgcn_s_barrier();
  STAGE(S1, 63);
  // iter 62: tile 62 landed (63 still in flight).
  WAITVM(4);
  __builtin_amdgcn_s_barrier();
  COMPUTE(S0);
  // iter 63: everything landed.
  WAITVM(0);
  __builtin_amdgcn_s_barrier();
  COMPUTE(S1);

#undef GLDS
#undef STAGE
#undef COMPUTE
#undef WAITVM

  // Epilogue butterfly. C/D mapping: col=lane&15, row=(lane>>4)*4+r.
#pragma unroll
  for (int im = 0; im < 4; ++im) {
    int rb = bm * BM + wm + im * 16 + (lane >> 4) * 4;
#pragma unroll
    for (int jn = 0; jn < 2; ++jn) {
      int p = bn * BN + wn + jn * 16 + lrow;
      float* lo = out + (size_t)rb * Nfull + p;
      float* hi = out + (size_t)rb * Nfull + (Nfull - 1 - p);
#pragma unroll
      for (int r = 0; r < 4; ++r) {
        float e = accE[im][jn][r];
        float o = accO[im][jn][r];
        lo[(size_t)r * Nfull] = e + o;
        hi[(size_t)r * Nfull] = e - o;
      }
    }
  }
}

extern "C" void kernel_launch(void* const* d_in, const int* in_sizes, int n_in,
                              void* d_out, int out_size, void* d_ws, size_t ws_size,
                              hipStream_t stream) {
  const float* x = (const float*)d_in[0];
  float* out = (float*)d_out;
  ushort_t* Ae = (ushort_t*)d_ws;                      // 16 MB (tiled)
  ushort_t* Ao = Ae + (size_t)8 * 1024 * 1024;         // 16 MB
  ushort_t* Ce = Ao + (size_t)8 * 1024 * 1024;         // 8 MB
  ushort_t* Co = Ce + (size_t)4 * 1024 * 1024;         // 8 MB

  prep_kernel<<<4096, 256, 0, stream>>>(x, Ae, Ao, Ce, Co);

  dim3 grid(Ph / BN, Md / BM);  // 16 x 32 = 512 blocks = 2/CU, 16 waves/CU
  gemm_fused<<<grid, 512, 0, stream>>>(Ae, Ao, Ce, Co, out);
}